// Round 1
// baseline (6196.456 us; speedup 1.0000x reference)
//
#include <hip/hip_runtime.h>
#include <math.h>

#define Bz   128
#define Cc   512
#define Hh   7
#define Ww   34
#define HW   238      // 7*34
#define ND   81
#define CH   529
#define KTOT (CH*HW)  // 125902
#define KS   64       // fc1 split-K factor

__device__ __forceinline__ float leaky(float x) { return x >= 0.f ? x : 0.1f * x; }

// ---------------------------------------------------------------------------
// corr81 + leaky -> xbuf channels [448, 529)
// block = (b, h) ; 256 threads loop over (d, w) pairs (81*34 = 2754)
// ---------------------------------------------------------------------------
__global__ __launch_bounds__(256) void corr_kernel(const float* __restrict__ left,
                                                   const float* __restrict__ right,
                                                   float* __restrict__ xbuf) {
    int bh = blockIdx.x;
    int b = bh / Hh, h = bh % Hh;
    const float* Lb = left  + (size_t)b * Cc * HW;
    const float* Rb = right + (size_t)b * Cc * HW;
    float* out = xbuf + ((size_t)b * CH + 448) * HW;

    for (int e = threadIdx.x; e < ND * Ww; e += blockDim.x) {
        int d = e / Ww, w = e - d * Ww;
        int dy = d / 9 - 4, dx = d - (d / 9) * 9 - 4;
        int hy = h + dy, wx = w + dx;
        float acc = 0.f;
        if (hy >= 0 && hy < Hh && wx >= 0 && wx < Ww) {
            const float* lp = Lb + h * Ww + w;
            const float* rp = Rb + hy * Ww + wx;
            #pragma unroll 8
            for (int c = 0; c < Cc; ++c) acc += lp[c * HW] * rp[c * HW];
        }
        acc *= (1.f / 512.f);
        out[(size_t)d * HW + h * Ww + w] = leaky(acc);
    }
}

// ---------------------------------------------------------------------------
// 3x3 conv (pad 1) + bias + leaky, 4 output channels per block
// reads xbuf channels [cin_base, 529), writes channels [oc_base+oc0, +4)
// ---------------------------------------------------------------------------
__global__ __launch_bounds__(256) void conv_kernel(float* __restrict__ xbuf,
                                                   const float* __restrict__ wgt,
                                                   const float* __restrict__ bias,
                                                   int IC, int cin_base, int oc_base,
                                                   int ocg_count) {
    int b   = blockIdx.x / ocg_count;
    int ocg = blockIdx.x - b * ocg_count;
    int oc0 = ocg * 4;
    int t = threadIdx.x;
    int h = t / Ww, w = t - h * Ww;
    bool active = (t < HW);

    const float* in = xbuf + ((size_t)b * CH + cin_base) * HW;
    float acc0 = 0.f, acc1 = 0.f, acc2 = 0.f, acc3 = 0.f;

    for (int ic = 0; ic < IC; ++ic) {
        const float* wp = wgt + ((size_t)oc0 * IC + ic) * 9;
        float w0[9], w1[9], w2[9], w3[9];
        #pragma unroll
        for (int i = 0; i < 9; ++i) {
            w0[i] = wp[i];
            w1[i] = wp[(size_t)IC * 9 + i];
            w2[i] = wp[(size_t)IC * 18 + i];
            w3[i] = wp[(size_t)IC * 27 + i];
        }
        if (active) {
            const float* ip = in + (size_t)ic * HW;
            #pragma unroll
            for (int ky = 0; ky < 3; ++ky) {
                int iy = h + ky - 1;
                if (iy < 0 || iy >= Hh) continue;
                #pragma unroll
                for (int kx = 0; kx < 3; ++kx) {
                    int ix = w + kx - 1;
                    if (ix < 0 || ix >= Ww) continue;
                    float v = ip[iy * Ww + ix];
                    int wi = ky * 3 + kx;
                    acc0 += v * w0[wi];
                    acc1 += v * w1[wi];
                    acc2 += v * w2[wi];
                    acc3 += v * w3[wi];
                }
            }
        }
    }
    if (active) {
        float* op = xbuf + ((size_t)b * CH + oc_base + oc0) * HW + t;
        op[0]               = leaky(acc0 + bias[oc0 + 0]);
        op[(size_t)HW]      = leaky(acc1 + bias[oc0 + 1]);
        op[(size_t)2 * HW]  = leaky(acc2 + bias[oc0 + 2]);
        op[(size_t)3 * HW]  = leaky(acc3 + bias[oc0 + 3]);
    }
}

// ---------------------------------------------------------------------------
// fc1: out[128,512] = x[128,125902] @ W[512,125902]^T, split-K partials
// grid (8 n-blocks of 64, KS k-splits); block 256; tile M=128 x N=64
// ---------------------------------------------------------------------------
__global__ __launch_bounds__(256) void fc1_kernel(const float* __restrict__ xbuf,
                                                  const float* __restrict__ wfc1,
                                                  float* __restrict__ part) {
    __shared__ float xs[128 * 33];
    __shared__ float wsm[64 * 33];
    int nb  = blockIdx.x;   // 0..7
    int ks  = blockIdx.y;   // 0..KS-1
    int tid = threadIdx.x;
    long long K = KTOT;
    int k0 = (int)((K * ks) / KS);
    int k1 = (int)((K * (ks + 1)) / KS);
    int tm = tid & 31;      // m base
    int tn = tid >> 5;      // n group (0..7)

    float acc[4][8];
    #pragma unroll
    for (int i = 0; i < 4; ++i)
        #pragma unroll
        for (int j = 0; j < 8; ++j) acc[i][j] = 0.f;

    for (int kc = k0; kc < k1; kc += 32) {
        #pragma unroll
        for (int i = 0; i < 16; ++i) {
            int lin = i * 256 + tid;
            int row = lin >> 5, kk = lin & 31;
            int k = kc + kk;
            xs[row * 33 + kk] = (k < k1) ? xbuf[(size_t)row * KTOT + k] : 0.f;
        }
        #pragma unroll
        for (int i = 0; i < 8; ++i) {
            int lin = i * 256 + tid;
            int row = lin >> 5, kk = lin & 31;
            int k = kc + kk;
            wsm[row * 33 + kk] = (k < k1) ? wfc1[(size_t)(nb * 64 + row) * KTOT + k] : 0.f;
        }
        __syncthreads();
        #pragma unroll 4
        for (int kk = 0; kk < 32; ++kk) {
            float a0 = xs[tm * 33 + kk];
            float a1 = xs[(tm + 32) * 33 + kk];
            float a2 = xs[(tm + 64) * 33 + kk];
            float a3 = xs[(tm + 96) * 33 + kk];
            #pragma unroll
            for (int j = 0; j < 8; ++j) {
                float wv = wsm[(tn * 8 + j) * 33 + kk];
                acc[0][j] += a0 * wv;
                acc[1][j] += a1 * wv;
                acc[2][j] += a2 * wv;
                acc[3][j] += a3 * wv;
            }
        }
        __syncthreads();
    }
    #pragma unroll
    for (int i = 0; i < 4; ++i) {
        int m = tm + 32 * i;
        float* pp = part + ((size_t)ks * Bz + m) * 512 + nb * 64 + tn * 8;
        #pragma unroll
        for (int j = 0; j < 8; ++j) pp[j] = acc[i][j];
    }
}

__global__ void zero_out(float* out) {
    if (threadIdx.x < 2) out[threadIdx.x] = 0.f;
}

// ---------------------------------------------------------------------------
// tail: reduce fc1 partials + bias + leaky -> h512; l1/r1; l2/r2;
// normalize; quat_dist; mean via atomicAdd. One block per batch element.
// ---------------------------------------------------------------------------
__global__ __launch_bounds__(256) void tail_kernel(const float* __restrict__ part,
                                                   const float* __restrict__ bfc1,
                                                   const float* __restrict__ wl1,
                                                   const float* __restrict__ bl1,
                                                   const float* __restrict__ wr1,
                                                   const float* __restrict__ br1,
                                                   const float* __restrict__ wl2,
                                                   const float* __restrict__ bl2,
                                                   const float* __restrict__ wr2,
                                                   const float* __restrict__ br2,
                                                   const float* __restrict__ ltgt,
                                                   const float* __restrict__ rtgt,
                                                   float* __restrict__ out) {
    int b = blockIdx.x;
    int tid = threadIdx.x;
    __shared__ float h512[512];
    __shared__ float lo[256], ro[256];
    __shared__ float q[8];

    for (int j = tid; j < 512; j += 256) {
        float s = bfc1[j];
        for (int ks = 0; ks < KS; ++ks) s += part[((size_t)ks * Bz + b) * 512 + j];
        h512[j] = leaky(s);
    }
    __syncthreads();
    {
        int n = tid;
        float sl = bl1[n], sr = br1[n];
        const float* wlp = wl1 + (size_t)n * 512;
        const float* wrp = wr1 + (size_t)n * 512;
        #pragma unroll 4
        for (int k = 0; k < 512; ++k) {
            float hv = h512[k];
            sl += hv * wlp[k];
            sr += hv * wrp[k];
        }
        lo[n] = leaky(sl);
        ro[n] = leaky(sr);
    }
    __syncthreads();
    if (tid < 8) {
        int i = tid & 3;
        bool isr = tid >= 4;
        const float* w2  = isr ? wr2 : wl2;
        const float* b2  = isr ? br2 : bl2;
        const float* src = isr ? ro : lo;
        float s = b2[i];
        for (int k = 0; k < 256; ++k) s += w2[i * 256 + k] * src[k];
        q[tid] = s;
    }
    __syncthreads();
    if (tid < 2) {
        const float* qq = q + tid * 4;
        const float* tg = (tid == 0 ? ltgt : rtgt) + (size_t)b * 4;
        float n2 = qq[0]*qq[0] + qq[1]*qq[1] + qq[2]*qq[2] + qq[3]*qq[3];
        float nrm = fmaxf(sqrtf(n2), 1e-12f);
        float qw = qq[0]/nrm, qx = qq[1]/nrm, qy = qq[2]/nrm, qz = qq[3]/nrm;
        float rw = tg[0], rx = -tg[1], ry = -tg[2], rz = -tg[3];
        float tw = qw*rw - qx*rx - qy*ry - qz*rz;
        float tx = qw*rx + qx*rw + qy*rz - qz*ry;
        float ty = qw*ry - qx*rz + qy*rw + qz*rx;
        float tz = qw*rz + qx*ry - qy*rx + qz*rw;
        float d = 2.f * atan2f(sqrtf(tx*tx + ty*ty + tz*tz + 1e-12f), fabsf(tw));
        atomicAdd(&out[tid], d * (1.f / 128.f));
    }
}

extern "C" void kernel_launch(void* const* d_in, const int* in_sizes, int n_in,
                              void* d_out, int out_size, void* d_ws, size_t ws_size,
                              hipStream_t stream) {
    const float* left  = (const float*)d_in[0];
    const float* right = (const float*)d_in[1];
    const float* ltgt  = (const float*)d_in[2];
    const float* rtgt  = (const float*)d_in[3];
    const float* w6[5] = {(const float*)d_in[4], (const float*)d_in[6], (const float*)d_in[8],
                          (const float*)d_in[10], (const float*)d_in[12]};
    const float* b6[5] = {(const float*)d_in[5], (const float*)d_in[7], (const float*)d_in[9],
                          (const float*)d_in[11], (const float*)d_in[13]};
    const float* wfc1 = (const float*)d_in[14];
    const float* bfc1 = (const float*)d_in[15];
    const float* wl1  = (const float*)d_in[16];
    const float* bl1  = (const float*)d_in[17];
    const float* wr1  = (const float*)d_in[18];
    const float* br1  = (const float*)d_in[19];
    const float* wl2  = (const float*)d_in[20];
    const float* bl2  = (const float*)d_in[21];
    const float* wr2  = (const float*)d_in[22];
    const float* br2  = (const float*)d_in[23];
    float* out  = (float*)d_out;
    float* xbuf = (float*)d_ws;                      // B*529*238 floats
    float* part = xbuf + (size_t)Bz * KTOT;          // KS*128*512 floats

    corr_kernel<<<dim3(Bz * Hh), 256, 0, stream>>>(left, right, xbuf);

    const int ICs[5]   = {81, 209, 337, 433, 497};
    const int cin[5]   = {448, 320, 192, 96, 32};
    const int OCs[5]   = {128, 128, 96, 64, 32};
    const int obase[5] = {320, 192, 96, 32, 0};
    for (int i = 0; i < 5; ++i) {
        int ocg = OCs[i] / 4;
        conv_kernel<<<dim3(Bz * ocg), 256, 0, stream>>>(xbuf, w6[i], b6[i],
                                                        ICs[i], cin[i], obase[i], ocg);
    }

    fc1_kernel<<<dim3(8, KS), 256, 0, stream>>>(xbuf, wfc1, part);
    zero_out<<<1, 64, 0, stream>>>(out);
    tail_kernel<<<dim3(Bz), 256, 0, stream>>>(part, bfc1, wl1, bl1, wr1, br1,
                                              wl2, bl2, wr2, br2, ltgt, rtgt, out);
}

// Round 2
// 1855.013 us; speedup vs baseline: 3.3404x; 3.3404x over previous
//
#include <hip/hip_runtime.h>
#include <math.h>

#define Bz   128
#define Cc   512
#define Hh   7
#define Ww   34
#define HW   238      // 7*34
#define ND   81
#define CH   529
#define KTOT (CH*HW)  // 125902
#define KS   64       // fc1 split-K factor

typedef short bf16x8 __attribute__((ext_vector_type(8)));
typedef float floatx16 __attribute__((ext_vector_type(16)));

__device__ __forceinline__ float leaky(float x) { return x >= 0.f ? x : 0.1f * x; }
__device__ __forceinline__ float b2f(ushort u) {
    unsigned int x = ((unsigned int)u) << 16;
    return __uint_as_float(x);
}
__device__ __forceinline__ ushort f2b(float f) {
    unsigned int u = __float_as_uint(f);
    u += 0x7fff + ((u >> 16) & 1);
    return (ushort)(u >> 16);
}

// ---------------------------------------------------------------------------
// weight pack: w[OC][IC][3][3] fp32 -> ap[9][OCp][ICp] bf16, zero-padded
// ---------------------------------------------------------------------------
__global__ __launch_bounds__(256) void pack_w(const float* __restrict__ w,
                                              ushort* __restrict__ ap,
                                              int OC, int IC, int OCp, int ICp) {
    int i = blockIdx.x * 256 + threadIdx.x;
    int tot = 9 * OCp * ICp;
    if (i >= tot) return;
    int ic = i % ICp;
    int r  = i / ICp;
    int oc = r % OCp;
    int kk = r / OCp;
    float v = (oc < OC && ic < IC) ? w[((size_t)(oc * IC + ic)) * 9 + kk] : 0.f;
    ap[i] = f2b(v);
}

// ---------------------------------------------------------------------------
// corr81 + leaky -> xbuf (bf16) channels [448, 529)
// ---------------------------------------------------------------------------
__global__ __launch_bounds__(256) void corr_kernel(const float* __restrict__ left,
                                                   const float* __restrict__ right,
                                                   ushort* __restrict__ xbuf) {
    int bh = blockIdx.x;
    int b = bh / Hh, h = bh % Hh;
    const float* Lb = left  + (size_t)b * Cc * HW;
    const float* Rb = right + (size_t)b * Cc * HW;
    ushort* out = xbuf + ((size_t)b * CH + 448) * HW;

    for (int e = threadIdx.x; e < ND * Ww; e += blockDim.x) {
        int d = e / Ww, w = e - d * Ww;
        int dy = d / 9 - 4, dx = d - (d / 9) * 9 - 4;
        int hy = h + dy, wx = w + dx;
        float acc = 0.f;
        if (hy >= 0 && hy < Hh && wx >= 0 && wx < Ww) {
            const float* lp = Lb + h * Ww + w;
            const float* rp = Rb + hy * Ww + wx;
            #pragma unroll 8
            for (int c = 0; c < Cc; ++c) acc += lp[c * HW] * rp[c * HW];
        }
        acc *= (1.f / 512.f);
        out[(size_t)d * HW + h * Ww + w] = f2b(leaky(acc));
    }
}

// ---------------------------------------------------------------------------
// implicit-GEMM 3x3 conv on MFMA 32x32x16 bf16.
// xbuf layout [b][529][238] bf16. A = packed weights [9][OCp][ICp].
// LDS: input chunk (32 ic) transposed to [spat 9x36][ic stride 40], zero border.
// block: 4 waves; wave = m-tile (wv&1) x 2 n-tiles; grid (B, mgroups*2).
// ---------------------------------------------------------------------------
__global__ __launch_bounds__(256) void conv_mfma(ushort* __restrict__ xbuf,
                                                 const ushort* __restrict__ apack,
                                                 const float* __restrict__ bias,
                                                 int IC, int ICp, int OC, int OCp,
                                                 int cin_base, int oc_base) {
    __shared__ ushort lds[324 * 40] __attribute__((aligned(16)));
    int b  = blockIdx.x;
    int mg = blockIdx.y >> 1;
    int ns = blockIdx.y & 1;
    int tid = threadIdx.x;
    int wv = tid >> 6, lane = tid & 63;
    int half = lane >> 5, l32 = lane & 31;

    // zero the padded border once (interior rewritten every chunk)
    for (int s = tid; s < 324; s += 256) {
        int r = s / 36, c = s - r * 36;
        if (r == 0 || r == 8 || c == 0 || c == 35) {
            unsigned int* p = (unsigned int*)&lds[s * 40];
            #pragma unroll
            for (int i = 0; i < 20; ++i) p[i] = 0u;
        }
    }

    int mtile  = wv & 1;
    int ntile0 = ns * 4 + (wv >> 1) * 2;  // wave covers ntile0, ntile0+1
    int mgbase = mg * 64 + mtile * 32;

    // LDS byte offsets for this lane's two n positions (clamped)
    int lofs0, lofs1;
    {
        int n = ntile0 * 32 + l32; if (n > 237) n = 237;
        int h = n / 34, w = n - h * 34;
        lofs0 = (((h + 1) * 36 + (w + 1)) * 40 + half * 8) * 2;
        n = ntile0 * 32 + 32 + l32; if (n > 237) n = 237;
        h = n / 34; w = n - h * 34;
        lofs1 = (((h + 1) * 36 + (w + 1)) * 40 + half * 8) * 2;
    }
    int oc_a = mgbase + l32;
    const ushort* abase = apack + (size_t)oc_a * ICp + half * 8;
    size_t akk = (size_t)OCp * ICp;

    floatx16 acc0 = (floatx16)0.0f;
    floatx16 acc1 = (floatx16)0.0f;

    int s_ic = tid >> 3, s_l = tid & 7;
    const ushort* grow = xbuf + ((size_t)b * CH + cin_base) * HW;

    int nchunk = ICp >> 5;
    for (int ci = 0; ci < nchunk; ++ci) {
        // ---- stage 32 input channels, transposed, into LDS ----
        int ic = ci * 32 + s_ic;
        const ushort* gr = grow + (size_t)ic * HW;
        bool icok = ic < IC;
        for (int hw = s_l; hw < HW; hw += 8) {
            ushort v = icok ? gr[hw] : (ushort)0;
            int h = hw / 34, w = hw - h * 34;
            lds[((h + 1) * 36 + (w + 1)) * 40 + s_ic] = v;
        }
        __syncthreads();

        const ushort* ab = abase + ci * 32;
        #pragma unroll
        for (int kk = 0; kk < 9; ++kk) {
            int ky = kk / 3, kx = kk - (kk / 3) * 3;
            int sofs = ((ky - 1) * 36 + (kx - 1)) * 80;  // bytes
            #pragma unroll
            for (int j = 0; j < 2; ++j) {
                bf16x8 av  = *(const bf16x8*)(ab + (size_t)kk * akk + j * 16);
                bf16x8 bv0 = *(const bf16x8*)((const char*)lds + lofs0 + sofs + j * 32);
                acc0 = __builtin_amdgcn_mfma_f32_32x32x16_bf16(av, bv0, acc0, 0, 0, 0);
                bf16x8 bv1 = *(const bf16x8*)((const char*)lds + lofs1 + sofs + j * 32);
                acc1 = __builtin_amdgcn_mfma_f32_32x32x16_bf16(av, bv1, acc1, 0, 0, 0);
            }
        }
        __syncthreads();
    }

    // ---- epilogue: C/D layout col=lane&31, row=(reg&3)+8*(reg>>2)+4*(lane>>5)
    ushort* outb = xbuf + ((size_t)b * CH + oc_base) * HW;
    int n0 = ntile0 * 32 + l32;
    int n1 = n0 + 32;
    #pragma unroll
    for (int r = 0; r < 16; ++r) {
        int m = (r & 3) + 8 * (r >> 2) + 4 * half;
        int ocg = mgbase + m;
        if (ocg < OC) {
            float bv = bias[ocg];
            if (n0 < HW) outb[(size_t)ocg * HW + n0] = f2b(leaky(acc0[r] + bv));
            if (n1 < HW) outb[(size_t)ocg * HW + n1] = f2b(leaky(acc1[r] + bv));
        }
    }
}

// ---------------------------------------------------------------------------
// fc1: out[128,512] = x[128,125902](bf16) @ W[512,125902]^T (fp32), split-K
// ---------------------------------------------------------------------------
__global__ __launch_bounds__(256) void fc1_kernel(const ushort* __restrict__ xbuf,
                                                  const float* __restrict__ wfc1,
                                                  float* __restrict__ part) {
    __shared__ float xs[128 * 33];
    __shared__ float wsm[64 * 33];
    int nb  = blockIdx.x;   // 0..7
    int ks  = blockIdx.y;   // 0..KS-1
    int tid = threadIdx.x;
    long long K = KTOT;
    int k0 = (int)((K * ks) / KS);
    int k1 = (int)((K * (ks + 1)) / KS);
    int tm = tid & 31;
    int tn = tid >> 5;

    float acc[4][8];
    #pragma unroll
    for (int i = 0; i < 4; ++i)
        #pragma unroll
        for (int j = 0; j < 8; ++j) acc[i][j] = 0.f;

    for (int kc = k0; kc < k1; kc += 32) {
        #pragma unroll
        for (int i = 0; i < 16; ++i) {
            int lin = i * 256 + tid;
            int row = lin >> 5, kk = lin & 31;
            int k = kc + kk;
            xs[row * 33 + kk] = (k < k1) ? b2f(xbuf[(size_t)row * KTOT + k]) : 0.f;
        }
        #pragma unroll
        for (int i = 0; i < 8; ++i) {
            int lin = i * 256 + tid;
            int row = lin >> 5, kk = lin & 31;
            int k = kc + kk;
            wsm[row * 33 + kk] = (k < k1) ? wfc1[(size_t)(nb * 64 + row) * KTOT + k] : 0.f;
        }
        __syncthreads();
        #pragma unroll 4
        for (int kk = 0; kk < 32; ++kk) {
            float a0 = xs[tm * 33 + kk];
            float a1 = xs[(tm + 32) * 33 + kk];
            float a2 = xs[(tm + 64) * 33 + kk];
            float a3 = xs[(tm + 96) * 33 + kk];
            #pragma unroll
            for (int j = 0; j < 8; ++j) {
                float wv = wsm[(tn * 8 + j) * 33 + kk];
                acc[0][j] += a0 * wv;
                acc[1][j] += a1 * wv;
                acc[2][j] += a2 * wv;
                acc[3][j] += a3 * wv;
            }
        }
        __syncthreads();
    }
    #pragma unroll
    for (int i = 0; i < 4; ++i) {
        int m = tm + 32 * i;
        float* pp = part + ((size_t)ks * Bz + m) * 512 + nb * 64 + tn * 8;
        #pragma unroll
        for (int j = 0; j < 8; ++j) pp[j] = acc[i][j];
    }
}

__global__ void zero_out(float* out) {
    if (threadIdx.x < 2) out[threadIdx.x] = 0.f;
}

// ---------------------------------------------------------------------------
// tail: reduce fc1 partials + bias + leaky -> h512; l1/r1; l2/r2; quat dist
// ---------------------------------------------------------------------------
__global__ __launch_bounds__(256) void tail_kernel(const float* __restrict__ part,
                                                   const float* __restrict__ bfc1,
                                                   const float* __restrict__ wl1,
                                                   const float* __restrict__ bl1,
                                                   const float* __restrict__ wr1,
                                                   const float* __restrict__ br1,
                                                   const float* __restrict__ wl2,
                                                   const float* __restrict__ bl2,
                                                   const float* __restrict__ wr2,
                                                   const float* __restrict__ br2,
                                                   const float* __restrict__ ltgt,
                                                   const float* __restrict__ rtgt,
                                                   float* __restrict__ out) {
    int b = blockIdx.x;
    int tid = threadIdx.x;
    __shared__ float h512[512];
    __shared__ float lo[256], ro[256];
    __shared__ float q[8];

    for (int j = tid; j < 512; j += 256) {
        float s = bfc1[j];
        for (int ks = 0; ks < KS; ++ks) s += part[((size_t)ks * Bz + b) * 512 + j];
        h512[j] = leaky(s);
    }
    __syncthreads();
    {
        int n = tid;
        float sl = bl1[n], sr = br1[n];
        const float* wlp = wl1 + (size_t)n * 512;
        const float* wrp = wr1 + (size_t)n * 512;
        #pragma unroll 4
        for (int k = 0; k < 512; ++k) {
            float hv = h512[k];
            sl += hv * wlp[k];
            sr += hv * wrp[k];
        }
        lo[n] = leaky(sl);
        ro[n] = leaky(sr);
    }
    __syncthreads();
    if (tid < 8) {
        int i = tid & 3;
        bool isr = tid >= 4;
        const float* w2  = isr ? wr2 : wl2;
        const float* b2  = isr ? br2 : bl2;
        const float* src = isr ? ro : lo;
        float s = b2[i];
        for (int k = 0; k < 256; ++k) s += w2[i * 256 + k] * src[k];
        q[tid] = s;
    }
    __syncthreads();
    if (tid < 2) {
        const float* qq = q + tid * 4;
        const float* tg = (tid == 0 ? ltgt : rtgt) + (size_t)b * 4;
        float n2 = qq[0]*qq[0] + qq[1]*qq[1] + qq[2]*qq[2] + qq[3]*qq[3];
        float nrm = fmaxf(sqrtf(n2), 1e-12f);
        float qw = qq[0]/nrm, qx = qq[1]/nrm, qy = qq[2]/nrm, qz = qq[3]/nrm;
        float rw = tg[0], rx = -tg[1], ry = -tg[2], rz = -tg[3];
        float tw = qw*rw - qx*rx - qy*ry - qz*rz;
        float tx = qw*rx + qx*rw + qy*rz - qz*ry;
        float ty = qw*ry - qx*rz + qy*rw + qz*rx;
        float tz = qw*rz + qx*ry - qy*rx + qz*rw;
        float d = 2.f * atan2f(sqrtf(tx*tx + ty*ty + tz*tz + 1e-12f), fabsf(tw));
        atomicAdd(&out[tid], d * (1.f / 128.f));
    }
}

extern "C" void kernel_launch(void* const* d_in, const int* in_sizes, int n_in,
                              void* d_out, int out_size, void* d_ws, size_t ws_size,
                              hipStream_t stream) {
    const float* left  = (const float*)d_in[0];
    const float* right = (const float*)d_in[1];
    const float* ltgt  = (const float*)d_in[2];
    const float* rtgt  = (const float*)d_in[3];
    const float* w6[5] = {(const float*)d_in[4], (const float*)d_in[6], (const float*)d_in[8],
                          (const float*)d_in[10], (const float*)d_in[12]};
    const float* b6[5] = {(const float*)d_in[5], (const float*)d_in[7], (const float*)d_in[9],
                          (const float*)d_in[11], (const float*)d_in[13]};
    const float* wfc1 = (const float*)d_in[14];
    const float* bfc1 = (const float*)d_in[15];
    const float* wl1  = (const float*)d_in[16];
    const float* bl1  = (const float*)d_in[17];
    const float* wr1  = (const float*)d_in[18];
    const float* br1  = (const float*)d_in[19];
    const float* wl2  = (const float*)d_in[20];
    const float* bl2  = (const float*)d_in[21];
    const float* wr2  = (const float*)d_in[22];
    const float* br2  = (const float*)d_in[23];
    float* out = (float*)d_out;

    // workspace layout (bytes)
    char* ws = (char*)d_ws;
    ushort* xbuf = (ushort*)ws;                                  // 128*529*238 bf16
    size_t xbuf_b = (size_t)Bz * CH * HW * sizeof(ushort);       // 32,230,912
    float* part = (float*)(ws + xbuf_b);                          // KS*128*512 f32
    size_t part_b = (size_t)KS * Bz * 512 * sizeof(float);        // 16,777,216
    ushort* apack = (ushort*)(ws + xbuf_b + part_b);

    const int ICs[5]   = {81, 209, 337, 433, 497};
    const int ICp[5]   = {96, 224, 352, 448, 512};
    const int OCs[5]   = {128, 128, 96, 64, 32};
    const int OCp[5]   = {128, 128, 128, 64, 64};
    const int cin[5]   = {448, 320, 192, 96, 32};
    const int obase[5] = {320, 192, 96, 32, 0};

    ushort* ap[5];
    size_t off = 0;
    for (int i = 0; i < 5; ++i) {
        ap[i] = apack + off;
        off += (size_t)9 * OCp[i] * ICp[i];
    }

    for (int i = 0; i < 5; ++i) {
        int tot = 9 * OCp[i] * ICp[i];
        pack_w<<<dim3((tot + 255) / 256), 256, 0, stream>>>(w6[i], ap[i],
                                                            OCs[i], ICs[i], OCp[i], ICp[i]);
    }

    corr_kernel<<<dim3(Bz * Hh), 256, 0, stream>>>(left, right, xbuf);

    for (int i = 0; i < 5; ++i) {
        int mgroups = OCp[i] / 64;
        conv_mfma<<<dim3(Bz, mgroups * 2), 256, 0, stream>>>(xbuf, ap[i], b6[i],
                                                             ICs[i], ICp[i], OCs[i], OCp[i],
                                                             cin[i], obase[i]);
    }

    fc1_kernel<<<dim3(8, KS), 256, 0, stream>>>(xbuf, wfc1, part);
    zero_out<<<1, 64, 0, stream>>>(out);
    tail_kernel<<<dim3(Bz), 256, 0, stream>>>(part, bfc1, wl1, bl1, wr1, br1,
                                              wl2, bl2, wr2, br2, ltgt, rtgt, out);
}

// Round 3
// 1153.503 us; speedup vs baseline: 5.3719x; 1.6082x over previous
//
#include <hip/hip_runtime.h>
#include <math.h>

#define Bz   128
#define Cc   512
#define Hh   7
#define Ww   34
#define HW   238       // 7*34
#define ND   81
#define CH   529
#define KTOT (CH*HW)   // 125902
#define XSTR 125904    // padded batch stride for xbuf (2 zero pad elems)
#define NCHK 7869      // ceil(KTOT/16)
#define KS   128       // fc1 split-K factor

typedef short bf16x8  __attribute__((ext_vector_type(8)));
typedef float floatx16 __attribute__((ext_vector_type(16)));
typedef float floatx4u __attribute__((ext_vector_type(4), aligned(4)));

__device__ __forceinline__ float leaky(float x) { return x >= 0.f ? x : 0.1f * x; }
__device__ __forceinline__ float b2f(ushort u) {
    unsigned int x = ((unsigned int)u) << 16;
    return __uint_as_float(x);
}
__device__ __forceinline__ ushort f2b(float f) {
    unsigned int u = __float_as_uint(f);
    u += 0x7fff + ((u >> 16) & 1);
    return (ushort)(u >> 16);
}

// ---------------------------------------------------------------------------
// weight pack: w[OC][IC][3][3] fp32 -> ap[9][OCp][ICp] bf16, zero-padded
// ---------------------------------------------------------------------------
__global__ __launch_bounds__(256) void pack_w(const float* __restrict__ w,
                                              ushort* __restrict__ ap,
                                              int OC, int IC, int OCp, int ICp) {
    int i = blockIdx.x * 256 + threadIdx.x;
    int tot = 9 * OCp * ICp;
    if (i >= tot) return;
    int ic = i % ICp;
    int r  = i / ICp;
    int oc = r % OCp;
    int kk = r / OCp;
    float v = (oc < OC && ic < IC) ? w[((size_t)(oc * IC + ic)) * 9 + kk] : 0.f;
    ap[i] = f2b(v);
}

// ---------------------------------------------------------------------------
// init: zero corr output region (invalid displacement entries must be 0)
// and the 2-element pad at the end of each batch row of xbuf
// ---------------------------------------------------------------------------
__global__ __launch_bounds__(256) void init_extra(ushort* __restrict__ xbuf) {
    int b = blockIdx.x;
    int t = threadIdx.x;
    unsigned int* dst = (unsigned int*)(xbuf + (size_t)b * XSTR + 448 * HW);
    for (int i = t; i < (ND * HW) / 2; i += 256) dst[i] = 0u;   // 81*238 shorts
    if (t < 2) xbuf[(size_t)b * XSTR + KTOT + t] = 0;
}

// ---------------------------------------------------------------------------
// corr81 via per-batch Gram matrix G[p][q] = sum_c L[c][p] R[c][q], MFMA bf16.
// grid (B, 4): blockIdx.y = mblk*2 + nblk; block covers 128 m x 128 n.
// Epilogue gathers valid displacements into xbuf channels [448,529).
// ---------------------------------------------------------------------------
__global__ __launch_bounds__(256) void corr_mfma(const float* __restrict__ left,
                                                 const float* __restrict__ right,
                                                 ushort* __restrict__ xbuf) {
    __shared__ short la[128 * 40] __attribute__((aligned(16)));
    __shared__ short lb[128 * 40] __attribute__((aligned(16)));
    int b = blockIdx.x;
    int mblk = blockIdx.y >> 1, nblk = blockIdx.y & 1;
    int m0 = mblk * 128, n0 = nblk * 128;
    int tid = threadIdx.x;
    int wv = tid >> 6, lane = tid & 63, half = lane >> 5, l32 = lane & 31;
    const float* Lb = left  + (size_t)b * Cc * HW;
    const float* Rb = right + (size_t)b * Cc * HW;

    int pl = tid >> 1;            // 0..127 local spatial row
    int c8 = (tid & 1) * 8;       // 0 or 8: which 8-channel half
    int pA = m0 + pl; bool okA = pA < HW;
    int pB = n0 + pl; bool okB = pB < HW;

    floatx16 acc[4];
    #pragma unroll
    for (int j = 0; j < 4; ++j) acc[j] = (floatx16)0.0f;

    int aofs = (wv * 32 + l32) * 40 + half * 8;

    for (int ck = 0; ck < 32; ++ck) {
        int c0 = ck * 16 + c8;
        bf16x8 va, vb;
        #pragma unroll
        for (int i = 0; i < 8; ++i) {
            va[i] = (short)f2b(okA ? Lb[(size_t)(c0 + i) * HW + pA] : 0.f);
            vb[i] = (short)f2b(okB ? Rb[(size_t)(c0 + i) * HW + pB] : 0.f);
        }
        __syncthreads();
        *(bf16x8*)&la[pl * 40 + c8] = va;
        *(bf16x8*)&lb[pl * 40 + c8] = vb;
        __syncthreads();
        bf16x8 av = *(const bf16x8*)&la[aofs];
        #pragma unroll
        for (int j = 0; j < 4; ++j) {
            bf16x8 bv = *(const bf16x8*)&lb[(j * 32 + l32) * 40 + half * 8];
            acc[j] = __builtin_amdgcn_mfma_f32_32x32x16_bf16(av, bv, acc[j], 0, 0, 0);
        }
    }

    // gather: (p,q) -> displacement d if |dy|<=4 && |dx|<=4
    #pragma unroll
    for (int j = 0; j < 4; ++j) {
        int q = n0 + j * 32 + l32;
        if (q >= HW) continue;
        int hq = q / 34, wq = q - hq * 34;
        #pragma unroll
        for (int r = 0; r < 16; ++r) {
            int p = m0 + wv * 32 + (r & 3) + 8 * (r >> 2) + 4 * half;
            if (p >= HW) continue;
            int hp = p / 34, wp = p - hp * 34;
            int dy = hq - hp, dx = wq - wp;
            if (dy >= -4 && dy <= 4 && dx >= -4 && dx <= 4) {
                int d = (dy + 4) * 9 + (dx + 4);
                xbuf[(size_t)b * XSTR + (size_t)(448 + d) * HW + p] =
                    f2b(leaky(acc[j][r] * (1.f / 512.f)));
            }
        }
    }
}

// ---------------------------------------------------------------------------
// implicit-GEMM 3x3 conv on MFMA 32x32x16 bf16 (unchanged from R2 except
// xbuf batch stride = XSTR).
// ---------------------------------------------------------------------------
__global__ __launch_bounds__(256) void conv_mfma(ushort* __restrict__ xbuf,
                                                 const ushort* __restrict__ apack,
                                                 const float* __restrict__ bias,
                                                 int IC, int ICp, int OC, int OCp,
                                                 int cin_base, int oc_base) {
    __shared__ ushort lds[324 * 40] __attribute__((aligned(16)));
    int b  = blockIdx.x;
    int mg = blockIdx.y >> 1;
    int ns = blockIdx.y & 1;
    int tid = threadIdx.x;
    int wv = tid >> 6, lane = tid & 63;
    int half = lane >> 5, l32 = lane & 31;

    for (int s = tid; s < 324; s += 256) {
        int r = s / 36, c = s - r * 36;
        if (r == 0 || r == 8 || c == 0 || c == 35) {
            unsigned int* p = (unsigned int*)&lds[s * 40];
            #pragma unroll
            for (int i = 0; i < 20; ++i) p[i] = 0u;
        }
    }

    int mtile  = wv & 1;
    int ntile0 = ns * 4 + (wv >> 1) * 2;
    int mgbase = mg * 64 + mtile * 32;

    int lofs0, lofs1;
    {
        int n = ntile0 * 32 + l32; if (n > 237) n = 237;
        int h = n / 34, w = n - h * 34;
        lofs0 = (((h + 1) * 36 + (w + 1)) * 40 + half * 8) * 2;
        n = ntile0 * 32 + 32 + l32; if (n > 237) n = 237;
        h = n / 34; w = n - h * 34;
        lofs1 = (((h + 1) * 36 + (w + 1)) * 40 + half * 8) * 2;
    }
    int oc_a = mgbase + l32;
    const ushort* abase = apack + (size_t)oc_a * ICp + half * 8;
    size_t akk = (size_t)OCp * ICp;

    floatx16 acc0 = (floatx16)0.0f;
    floatx16 acc1 = (floatx16)0.0f;

    int s_ic = tid >> 3, s_l = tid & 7;
    const ushort* grow = xbuf + (size_t)b * XSTR + (size_t)cin_base * HW;

    int nchunk = ICp >> 5;
    for (int ci = 0; ci < nchunk; ++ci) {
        int ic = ci * 32 + s_ic;
        const ushort* gr = grow + (size_t)ic * HW;
        bool icok = ic < IC;
        for (int hw = s_l; hw < HW; hw += 8) {
            ushort v = icok ? gr[hw] : (ushort)0;
            int h = hw / 34, w = hw - h * 34;
            lds[((h + 1) * 36 + (w + 1)) * 40 + s_ic] = v;
        }
        __syncthreads();

        const ushort* ab = abase + ci * 32;
        #pragma unroll
        for (int kk = 0; kk < 9; ++kk) {
            int ky = kk / 3, kx = kk - (kk / 3) * 3;
            int sofs = ((ky - 1) * 36 + (kx - 1)) * 80;
            #pragma unroll
            for (int j = 0; j < 2; ++j) {
                bf16x8 av  = *(const bf16x8*)(ab + (size_t)kk * akk + j * 16);
                bf16x8 bv0 = *(const bf16x8*)((const char*)lds + lofs0 + sofs + j * 32);
                acc0 = __builtin_amdgcn_mfma_f32_32x32x16_bf16(av, bv0, acc0, 0, 0, 0);
                bf16x8 bv1 = *(const bf16x8*)((const char*)lds + lofs1 + sofs + j * 32);
                acc1 = __builtin_amdgcn_mfma_f32_32x32x16_bf16(av, bv1, acc1, 0, 0, 0);
            }
        }
        __syncthreads();
    }

    ushort* outb = xbuf + (size_t)b * XSTR + (size_t)oc_base * HW;
    int n0 = ntile0 * 32 + l32;
    int n1 = n0 + 32;
    #pragma unroll
    for (int r = 0; r < 16; ++r) {
        int m = (r & 3) + 8 * (r >> 2) + 4 * half;
        int ocg = mgbase + m;
        if (ocg < OC) {
            float bv = bias[ocg];
            if (n0 < HW) outb[(size_t)ocg * HW + n0] = f2b(leaky(acc0[r] + bv));
            if (n1 < HW) outb[(size_t)ocg * HW + n1] = f2b(leaky(acc1[r] + bv));
        }
    }
}

// ---------------------------------------------------------------------------
// fc1 as streaming MFMA GEMM: part[ks][b][m] += w[m][k]*x[b][k] over k-split.
// A = wfc1 fp32 (converted to bf16 in-register, streamed once), B = xbuf bf16.
// grid (4 m-groups, KS k-splits), block 256 = 4 waves; wave = 32m x 128n.
// ---------------------------------------------------------------------------
__global__ __launch_bounds__(256) void fc1_mfma(const ushort* __restrict__ xbuf,
                                                const float* __restrict__ wfc1,
                                                float* __restrict__ part) {
    int mg = blockIdx.x;    // 0..3
    int ks = blockIdx.y;    // 0..KS-1
    int tid = threadIdx.x;
    int wv = tid >> 6, lane = tid & 63, half = lane >> 5, l32 = lane & 31;
    int m_base = mg * 128 + wv * 32;
    const float* wrow = wfc1 + (size_t)(m_base + l32) * KTOT + half * 8;

    int c0 = (int)(((long long)NCHK * ks) / KS);
    int c1 = (int)(((long long)NCHK * (ks + 1)) / KS);

    floatx16 acc[4];
    #pragma unroll
    for (int j = 0; j < 4; ++j) acc[j] = (floatx16)0.0f;

    for (int c = c0; c < c1; ++c) {
        int k0 = c * 16;
        bf16x8 av;
        if (k0 + 16 <= KTOT) {
            floatx4u f0 = *(const floatx4u*)(wrow + k0);
            floatx4u f1 = *(const floatx4u*)(wrow + k0 + 4);
            #pragma unroll
            for (int i = 0; i < 4; ++i) {
                av[i]     = (short)f2b(f0[i]);
                av[4 + i] = (short)f2b(f1[i]);
            }
        } else {
            #pragma unroll
            for (int i = 0; i < 8; ++i) {
                int k = k0 + half * 8 + i;
                av[i] = (k < KTOT) ? (short)f2b(wrow[k0 + i]) : (short)0;
            }
        }
        #pragma unroll
        for (int j = 0; j < 4; ++j) {
            bf16x8 bv = *(const bf16x8*)(xbuf + (size_t)(j * 32 + l32) * XSTR + k0 + half * 8);
            acc[j] = __builtin_amdgcn_mfma_f32_32x32x16_bf16(av, bv, acc[j], 0, 0, 0);
        }
    }

    #pragma unroll
    for (int j = 0; j < 4; ++j) {
        int bn = j * 32 + l32;
        float* pp = part + ((size_t)ks * Bz + bn) * 512 + m_base;
        #pragma unroll
        for (int r = 0; r < 16; ++r)
            pp[(r & 3) + 8 * (r >> 2) + 4 * half] = acc[j][r];
    }
}

__global__ void zero_out(float* out) {
    if (threadIdx.x < 2) out[threadIdx.x] = 0.f;
}

// ---------------------------------------------------------------------------
// tail: reduce fc1 partials + bias + leaky -> h512; l1/r1; l2/r2; quat dist
// ---------------------------------------------------------------------------
__global__ __launch_bounds__(256) void tail_kernel(const float* __restrict__ part,
                                                   const float* __restrict__ bfc1,
                                                   const float* __restrict__ wl1,
                                                   const float* __restrict__ bl1,
                                                   const float* __restrict__ wr1,
                                                   const float* __restrict__ br1,
                                                   const float* __restrict__ wl2,
                                                   const float* __restrict__ bl2,
                                                   const float* __restrict__ wr2,
                                                   const float* __restrict__ br2,
                                                   const float* __restrict__ ltgt,
                                                   const float* __restrict__ rtgt,
                                                   float* __restrict__ out) {
    int b = blockIdx.x;
    int tid = threadIdx.x;
    __shared__ float h512[512];
    __shared__ float lo[256], ro[256];
    __shared__ float q[8];

    for (int j = tid; j < 512; j += 256) {
        float s = bfc1[j];
        for (int ks = 0; ks < KS; ++ks) s += part[((size_t)ks * Bz + b) * 512 + j];
        h512[j] = leaky(s);
    }
    __syncthreads();
    {
        int n = tid;
        float sl = bl1[n], sr = br1[n];
        const float* wlp = wl1 + (size_t)n * 512;
        const float* wrp = wr1 + (size_t)n * 512;
        #pragma unroll 4
        for (int k = 0; k < 512; ++k) {
            float hv = h512[k];
            sl += hv * wlp[k];
            sr += hv * wrp[k];
        }
        lo[n] = leaky(sl);
        ro[n] = leaky(sr);
    }
    __syncthreads();
    if (tid < 8) {
        int i = tid & 3;
        bool isr = tid >= 4;
        const float* w2  = isr ? wr2 : wl2;
        const float* b2  = isr ? br2 : bl2;
        const float* src = isr ? ro : lo;
        float s = b2[i];
        for (int k = 0; k < 256; ++k) s += w2[i * 256 + k] * src[k];
        q[tid] = s;
    }
    __syncthreads();
    if (tid < 2) {
        const float* qq = q + tid * 4;
        const float* tg = (tid == 0 ? ltgt : rtgt) + (size_t)b * 4;
        float n2 = qq[0]*qq[0] + qq[1]*qq[1] + qq[2]*qq[2] + qq[3]*qq[3];
        float nrm = fmaxf(sqrtf(n2), 1e-12f);
        float qw = qq[0]/nrm, qx = qq[1]/nrm, qy = qq[2]/nrm, qz = qq[3]/nrm;
        float rw = tg[0], rx = -tg[1], ry = -tg[2], rz = -tg[3];
        float tw = qw*rw - qx*rx - qy*ry - qz*rz;
        float tx = qw*rx + qx*rw + qy*rz - qz*ry;
        float ty = qw*ry - qx*rz + qy*rw + qz*rx;
        float tz = qw*rz + qx*ry - qy*rx + qz*rw;
        float d = 2.f * atan2f(sqrtf(tx*tx + ty*ty + tz*tz + 1e-12f), fabsf(tw));
        atomicAdd(&out[tid], d * (1.f / 128.f));
    }
}

extern "C" void kernel_launch(void* const* d_in, const int* in_sizes, int n_in,
                              void* d_out, int out_size, void* d_ws, size_t ws_size,
                              hipStream_t stream) {
    const float* left  = (const float*)d_in[0];
    const float* right = (const float*)d_in[1];
    const float* ltgt  = (const float*)d_in[2];
    const float* rtgt  = (const float*)d_in[3];
    const float* w6[5] = {(const float*)d_in[4], (const float*)d_in[6], (const float*)d_in[8],
                          (const float*)d_in[10], (const float*)d_in[12]};
    const float* b6[5] = {(const float*)d_in[5], (const float*)d_in[7], (const float*)d_in[9],
                          (const float*)d_in[11], (const float*)d_in[13]};
    const float* wfc1 = (const float*)d_in[14];
    const float* bfc1 = (const float*)d_in[15];
    const float* wl1  = (const float*)d_in[16];
    const float* bl1  = (const float*)d_in[17];
    const float* wr1  = (const float*)d_in[18];
    const float* br1  = (const float*)d_in[19];
    const float* wl2  = (const float*)d_in[20];
    const float* bl2  = (const float*)d_in[21];
    const float* wr2  = (const float*)d_in[22];
    const float* br2  = (const float*)d_in[23];
    float* out = (float*)d_out;

    // workspace layout
    char* ws = (char*)d_ws;
    ushort* xbuf = (ushort*)ws;                                   // 128*125904 bf16
    size_t xbuf_b = (size_t)Bz * XSTR * sizeof(ushort);           // 32,231,424
    float* part = (float*)(ws + xbuf_b);                          // KS*128*512 f32
    size_t part_b = (size_t)KS * Bz * 512 * sizeof(float);        // 33,554,432
    ushort* apack = (ushort*)(ws + xbuf_b + part_b);              // ~2.7 MB

    const int ICs[5]   = {81, 209, 337, 433, 497};
    const int ICp[5]   = {96, 224, 352, 448, 512};
    const int OCs[5]   = {128, 128, 96, 64, 32};
    const int OCp[5]   = {128, 128, 128, 64, 64};
    const int cin[5]   = {448, 320, 192, 96, 32};
    const int obase[5] = {320, 192, 96, 32, 0};

    ushort* ap[5];
    size_t off = 0;
    for (int i = 0; i < 5; ++i) {
        ap[i] = apack + off;
        off += (size_t)9 * OCp[i] * ICp[i];
    }

    for (int i = 0; i < 5; ++i) {
        int tot = 9 * OCp[i] * ICp[i];
        pack_w<<<dim3((tot + 255) / 256), 256, 0, stream>>>(w6[i], ap[i],
                                                            OCs[i], ICs[i], OCp[i], ICp[i]);
    }

    init_extra<<<dim3(Bz), 256, 0, stream>>>(xbuf);
    corr_mfma<<<dim3(Bz, 4), 256, 0, stream>>>(left, right, xbuf);

    for (int i = 0; i < 5; ++i) {
        int mgroups = OCp[i] / 64;
        conv_mfma<<<dim3(Bz, mgroups * 2), 256, 0, stream>>>(xbuf, ap[i], b6[i],
                                                             ICs[i], ICp[i], OCs[i], OCp[i],
                                                             cin[i], obase[i]);
    }

    fc1_mfma<<<dim3(4, KS), 256, 0, stream>>>(xbuf, wfc1, part);
    zero_out<<<1, 64, 0, stream>>>(out);
    tail_kernel<<<dim3(Bz), 256, 0, stream>>>(part, bfc1, wl1, bl1, wr1, br1,
                                              wl2, bl2, wr2, br2, ltgt, rtgt, out);
}